// Round 8
// baseline (36.873 us; speedup 1.0000x reference)
//
#include <hip/hip_runtime.h>
#include <math.h>

#define NPTS_C 100
#define EPS_C 1e-8

#if defined(__has_builtin)
# if __has_builtin(__builtin_amdgcn_exp2f)
#  define FAST_EXP2(x) __builtin_amdgcn_exp2f(x)
# else
#  define FAST_EXP2(x) exp2f(x)
# endif
#else
# define FAST_EXP2(x) exp2f(x)
#endif

__device__ __forceinline__ float dot4(float4 a, float4 b) {
    return a.x * b.x + a.y * b.y + a.z * b.z + a.w * b.w;
}

__device__ __forceinline__ float wave_reduce_sum(float v) {
#pragma unroll
    for (int m = 1; m < 64; m <<= 1)
        v += __shfl_xor(v, m, 64);
    return v;
}

// ---------------- fast path constants (C=512, K=10, NPTS=100) --------------
constexpr int KC   = 10;
constexpr int NTAB = 550;   // sum_{i=1..10} 10*i

// Block = 256 threads = 4 waves; each wave owns 16 rows as TWO groups of 8,
// software-pipelined: the 2nd group's loads are issued before the 1st
// group's quadrature, so VMEM latency hides under ~2000 cycles of compute.
// Layout within a group: row = lane&7, part = lane>>3 (8 lanes per row).
// Grid = B/64 = 1024 blocks = exactly 4 resident blocks/CU (no churn).
__global__ __launch_bounds__(256, 4) void fused512_kernel(
    const float* __restrict__ x, const float* __restrict__ Wa,
    const float* __restrict__ ba, const float* __restrict__ Wb,
    const float* __restrict__ bb, float* __restrict__ out)
{
    __shared__ __align__(16) float2 s_tab[NTAB];   // (log2 g, log2(1-g)), fp32 grid
    __shared__ __align__(16) float4 s_w4[256];     // [0..127] Wa, [128..255] Wb

    const int tid = threadIdx.x;

    if (tid < 128) {
        s_w4[tid]       = reinterpret_cast<const float4*>(Wa)[tid];
        s_w4[128 + tid] = reinterpret_cast<const float4*>(Wb)[tid];
    }

    // row-invariant log2 tables (fp32 grid, matches ref; last point of last
    // segment rounds to 1.0f -> log2f(0) = -inf -> exp2 -> 0)
    {
        int base = 0;
#pragma unroll
        for (int i = 1; i <= KC; ++i) {
            const int n = 10 * i;
            const double start = EPS_C;
            const double stop  = (double)i / (double)KC - EPS_C;
            const double step  = (stop - start) / (double)(n - 1);
            for (int j = tid; j < n; j += 256) {
                const double g = (j == n - 1) ? stop : start + step * (double)j;
                const float g32 = (float)g;
                s_tab[base + j] = make_float2(log2f(g32), log2f(1.0f - g32));
            }
            base += n;
        }
    }
    __syncthreads();

    const int lane = tid & 63;
    const int wv   = tid >> 6;
    const int r8   = lane & 7;    // which of the group's 8 rows
    const int part = lane >> 3;   // 0..7: this lane's slice of the row
    const float ba0 = ba[0], bb0 = bb[0];

    // this wave's 16 rows: [rowBase, rowBase+16)
    const int rowBase = blockIdx.x * 64 + wv * 16;

    float4 xv[16];

#define LOAD_GROUP(row0)                                                     \
    {                                                                        \
        const float* px = x + (size_t)((row0) + r8) * 512 + part * 4;        \
        _Pragma("unroll")                                                    \
        for (int j = 0; j < 16; ++j)                                         \
            xv[j] = *reinterpret_cast<const float4*>(px + (size_t)j * 32);   \
    }

#define DOTS(da, db)                                                         \
    {                                                                        \
        da = 0.f; db = 0.f;                                                  \
        _Pragma("unroll")                                                    \
        for (int j = 0; j < 16; ++j) {                                       \
            const float4 wa = s_w4[part + 8 * j];                            \
            const float4 wb = s_w4[128 + part + 8 * j];                      \
            da += dot4(xv[j], wa);                                           \
            db += dot4(xv[j], wb);                                           \
        }                                                                    \
        da += __shfl_xor(da, 8, 64);  db += __shfl_xor(db, 8, 64);           \
        da += __shfl_xor(da, 16, 64); db += __shfl_xor(db, 16, 64);          \
        da += __shfl_xor(da, 32, 64); db += __shfl_xor(db, 32, 64);          \
        da += ba0; db += bb0;                                                \
    }

#define QUAD_STORE(row0, da, db)                                             \
    {                                                                        \
        const float sa = fmaxf(da, 0.f) + log1pf(expf(-fabsf(da)));          \
        const float sb = fmaxf(db, 0.f) + log1pf(expf(-fabsf(db)));          \
        const float alpha = fminf(fmaxf(1.f + sa, 1.f), 100.f);              \
        const float beta  = fminf(fmaxf(1.f + sb, 1.f), 100.f);              \
        const float am1 = alpha - 1.f, bm1 = beta - 1.f;                     \
        const float den = am1 + bm1;                                         \
        float mm = (den > 0.f) ? am1 / den : 0.5f;                           \
        mm = fminf(fmaxf(mm, 1e-6f), 1.f - 1e-6f);                           \
        const float M2 = am1 * log2f(mm) + bm1 * log2f(1.f - mm);            \
        float seg[KC];                                                       \
        int base = 0;                                                        \
        _Pragma("unroll")                                                    \
        for (int i = 1; i <= KC; ++i) {                                      \
            const int n = 10 * i;                                            \
            float s = 0.f;                                                   \
            for (int t = part; t < n; t += 8) {                              \
                const float2 e = s_tab[base + t];                            \
                s += FAST_EXP2(fmaf(am1, e.x, fmaf(bm1, e.y, -M2)));         \
            }                                                                \
            seg[i - 1] = s;                                                  \
            base += n;                                                       \
        }                                                                    \
        _Pragma("unroll")                                                    \
        for (int i = 0; i < KC; ++i) {                                       \
            seg[i] += __shfl_xor(seg[i], 8, 64);                             \
            seg[i] += __shfl_xor(seg[i], 16, 64);                            \
            seg[i] += __shfl_xor(seg[i], 32, 64);                            \
        }                                                                    \
        if (part == 0) {                                                     \
            float2* o2 = reinterpret_cast<float2*>(                          \
                out + (size_t)((row0) + r8) * KC);                           \
            const float inv_total = 1.f / seg[KC - 1];                       \
            float prev = 0.f;                                                \
            _Pragma("unroll")                                                \
            for (int j = 0; j < KC; j += 2) {                                \
                const float p0 = (seg[j]     - prev)   * inv_total;          \
                const float p1 = (seg[j + 1] - seg[j]) * inv_total;          \
                o2[j >> 1] = make_float2(p0, p1);                            \
                prev = seg[j + 1];                                           \
            }                                                                \
        }                                                                    \
    }

    // ---- pipelined: load(g0) / dots(g0) / load(g1) / quad(g0) / dots(g1)
    //      / quad(g1).  xv is dead after DOTS, so one buffer suffices. ----
    float da0, db0, da1, db1;
    LOAD_GROUP(rowBase);
    DOTS(da0, db0);
    LOAD_GROUP(rowBase + 8);          // in flight during quad of group 0
    QUAD_STORE(rowBase, da0, db0);
    DOTS(da1, db1);
    QUAD_STORE(rowBase + 8, da1, db1);

#undef LOAD_GROUP
#undef DOTS
#undef QUAD_STORE
}

// ---------------- Fallback: round-1 fused kernel (passed) ------------------
__global__ __launch_bounds__(256, 4) void ub_fused_kernel(
    const float* __restrict__ x, const float* __restrict__ Wa,
    const float* __restrict__ ba, const float* __restrict__ Wb,
    const float* __restrict__ bb, float* __restrict__ out,
    int B, int C, int K)
{
    __shared__ __align__(16) float s_lg[600];
    __shared__ __align__(16) float s_l1g[600];
    __shared__ __align__(16) float s_w[1024];

    const int tid = threadIdx.x;
    for (int c = tid; c < C; c += blockDim.x) {
        s_w[c]     = Wa[c];
        s_w[C + c] = Wb[c];
    }
    {
        int base = 0;
        for (int i = 1; i <= K; ++i) {
            const int n = (int)((double)NPTS_C * ((double)i / (double)K));
            const double start = EPS_C;
            const double stop  = (double)i / (double)K - EPS_C;
            const double step  = (n > 1) ? (stop - start) / (double)(n - 1) : 0.0;
            for (int j = tid; j < n; j += blockDim.x) {
                float g = (j == n - 1) ? (float)stop : (float)(start + step * (double)j);
                s_lg[base + j]  = logf(g);
                s_l1g[base + j] = log1pf(-g);
            }
            base += n;
        }
    }
    __syncthreads();

    const float ba0 = ba[0], bb0 = bb[0];
    const int wave = tid >> 6;
    const int lane = tid & 63;
    const int wavesPerBlock = blockDim.x >> 6;
    const int waveId = blockIdx.x * wavesPerBlock + wave;
    const int nWaves = gridDim.x * wavesPerBlock;

    for (int row = waveId; row < B; row += nWaves) {
        const float* xr = x + (size_t)row * C;
        float da = 0.f, db = 0.f;
        for (int c0 = 0; c0 < C; c0 += 256) {
            const float4 xv = *reinterpret_cast<const float4*>(xr + c0 + 4 * lane);
            const float4 wa = *reinterpret_cast<const float4*>(&s_w[c0 + 4 * lane]);
            const float4 wb = *reinterpret_cast<const float4*>(&s_w[C + c0 + 4 * lane]);
            da += xv.x * wa.x + xv.y * wa.y + xv.z * wa.z + xv.w * wa.w;
            db += xv.x * wb.x + xv.y * wb.y + xv.z * wb.z + xv.w * wb.w;
        }
        da = wave_reduce_sum(da) + ba0;
        db = wave_reduce_sum(db) + bb0;

        const float sa = fmaxf(da, 0.f) + log1pf(expf(-fabsf(da)));
        const float sb = fmaxf(db, 0.f) + log1pf(expf(-fabsf(db)));
        const float alpha = fminf(fmaxf(1.f + sa, 1.f), 100.f);
        const float beta  = fminf(fmaxf(1.f + sb, 1.f), 100.f);
        const float log_norm = lgammaf(alpha) + lgammaf(beta) - lgammaf(alpha + beta);
        const float am1 = alpha - 1.f, bm1 = beta - 1.f;

        float cdf_prev = 0.f, myp = 0.f;
        int base = 0;
        for (int i = 1; i <= K; ++i) {
            const int n = (int)((double)NPTS_C * ((double)i / (double)K));
            float s = 0.f;
            for (int p = lane; p < n; p += 64) {
                const float lp = fmaf(am1, s_lg[base + p],
                                 fmaf(bm1, s_l1g[base + p], -log_norm));
                s += expf(lp);
            }
            const float cdf = wave_reduce_sum(s);
            if (lane == i - 1) myp = cdf - cdf_prev;
            cdf_prev = cdf;
            base += n;
        }
        if (lane < K)
            out[(size_t)row * K + lane] = myp / cdf_prev;
    }
}

extern "C" void kernel_launch(void* const* d_in, const int* in_sizes, int n_in,
                              void* d_out, int out_size, void* d_ws, size_t ws_size,
                              hipStream_t stream) {
    const float* x  = (const float*)d_in[0];
    const float* Wa = (const float*)d_in[1];
    const float* ba = (const float*)d_in[2];
    const float* Wb = (const float*)d_in[3];
    const float* bb = (const float*)d_in[4];
    float* out = (float*)d_out;

    const int C = in_sizes[1];           // 512
    const int B = in_sizes[0] / C;       // 65536
    const int K = out_size / B;          // 10

    const bool fast_ok = (C == 512) && (K == 10) && (B % 64 == 0);

    if (fast_ok) {
        fused512_kernel<<<B / 64, 256, 0, stream>>>(x, Wa, ba, Wb, bb, out);
    } else {
        int nblocks = (B + 3) / 4;
        if (nblocks > 2048) nblocks = 2048;
        ub_fused_kernel<<<nblocks, 256, 0, stream>>>(x, Wa, ba, Wb, bb, out, B, C, K);
    }
}

// Round 9
// 33.909 us; speedup vs baseline: 1.0874x; 1.0874x over previous
//
#include <hip/hip_runtime.h>
#include <math.h>

#define NPTS_C 100
#define EPS_C 1e-8

#if defined(__has_builtin)
# if __has_builtin(__builtin_amdgcn_exp2f)
#  define FAST_EXP2(x) __builtin_amdgcn_exp2f(x)
#  define FAST_LOG2(x) __builtin_amdgcn_logf(x)
# else
#  define FAST_EXP2(x) exp2f(x)
#  define FAST_LOG2(x) log2f(x)
# endif
#else
# define FAST_EXP2(x) exp2f(x)
# define FAST_LOG2(x) log2f(x)
#endif

#define LOG2E_F 1.44269504088896340736f
#define LN2_F   0.69314718055994530942f

__device__ __forceinline__ float dot4(float4 a, float4 b) {
    return a.x * b.x + a.y * b.y + a.z * b.z + a.w * b.w;
}

__device__ __forceinline__ float wave_reduce_sum(float v) {
#pragma unroll
    for (int m = 1; m < 64; m <<= 1)
        v += __shfl_xor(v, m, 64);
    return v;
}

// ---------------- fast path constants (C=512, K=10, NPTS=100) --------------
constexpr int KC   = 10;
constexpr int NTAB = 550;   // sum_{i=1..10} 10*i

// Block = 256 threads = 4 waves; each wave owns 8 rows (grid = B/32 = 2048).
// Layout: row = lane&7, part = lane>>3 (8 lanes per row) -> per load instr
// the wave covers 8 rows x 128 contiguous bytes (fully-used cache lines).
// Loads are fused with their dot consumption (no xv[16] array) -> ~60 VGPR
// -> 6 waves/SIMD (24 waves/CU), so co-resident waves hide HBM/LDS latency.
__global__ __launch_bounds__(256, 6) void fused512_kernel(
    const float* __restrict__ x, const float* __restrict__ Wa,
    const float* __restrict__ ba, const float* __restrict__ Wb,
    const float* __restrict__ bb, float* __restrict__ out)
{
    __shared__ __align__(16) float2 s_tab[NTAB];   // (log2 g, log2(1-g)), fp32 grid
    __shared__ __align__(16) float4 s_w4[256];     // [0..127] Wa, [128..255] Wb

    const int tid = threadIdx.x;

    if (tid < 128) {
        s_w4[tid]       = reinterpret_cast<const float4*>(Wa)[tid];
        s_w4[128 + tid] = reinterpret_cast<const float4*>(Wb)[tid];
    }

    // row-invariant log2 tables (fp32 grid, matches ref; last point of last
    // segment rounds to 1.0f -> log2f(0) = -inf -> exp2 -> 0)
    {
        int base = 0;
#pragma unroll
        for (int i = 1; i <= KC; ++i) {
            const int n = 10 * i;
            const double start = EPS_C;
            const double stop  = (double)i / (double)KC - EPS_C;
            const double step  = (stop - start) / (double)(n - 1);
            for (int j = tid; j < n; j += 256) {
                const double g = (j == n - 1) ? stop : start + step * (double)j;
                const float g32 = (float)g;
                s_tab[base + j] = make_float2(log2f(g32), log2f(1.0f - g32));
            }
            base += n;
        }
    }
    __syncthreads();

    const int lane = tid & 63;
    const int wv   = tid >> 6;
    const int r8   = lane & 7;    // which of the wave's 8 rows
    const int part = lane >> 3;   // 0..7: this lane's slice of the row
    const float ba0 = ba[0], bb0 = bb[0];

    const int row = blockIdx.x * 32 + wv * 8 + r8;
    const float* px = x + (size_t)row * 512 + part * 4;

    // ---- phase 1: load-and-dot, 2 accumulator pairs for ILP ----
    float da = 0.f, db = 0.f, da2 = 0.f, db2 = 0.f;
#pragma unroll
    for (int j = 0; j < 16; j += 2) {
        const float4 x0 = *reinterpret_cast<const float4*>(px + (size_t)j * 32);
        const float4 x1 = *reinterpret_cast<const float4*>(px + (size_t)(j + 1) * 32);
        da  += dot4(x0, s_w4[part + 8 * j]);
        db  += dot4(x0, s_w4[128 + part + 8 * j]);
        da2 += dot4(x1, s_w4[part + 8 * (j + 1)]);
        db2 += dot4(x1, s_w4[128 + part + 8 * (j + 1)]);
    }
    da += da2; db += db2;

    // reduce across the 8 lanes holding this row (all 8 rows at once)
    da += __shfl_xor(da, 8, 64);  db += __shfl_xor(db, 8, 64);
    da += __shfl_xor(da, 16, 64); db += __shfl_xor(db, 16, 64);
    da += __shfl_xor(da, 32, 64); db += __shfl_xor(db, 32, 64);
    da += ba0; db += bb0;

    // ---- per-row scalars (8-way redundant; hw exp2/log2 forms) ----
    // softplus(x) = max(x,0) + log1p(exp(-|x|));  log1p(u) = log2(1+u)*ln2
    const float ua = FAST_EXP2(-fabsf(da) * LOG2E_F);
    const float ub = FAST_EXP2(-fabsf(db) * LOG2E_F);
    const float sa = fmaxf(da, 0.f) + FAST_LOG2(1.f + ua) * LN2_F;
    const float sb = fmaxf(db, 0.f) + FAST_LOG2(1.f + ub) * LN2_F;
    const float alpha = fminf(fmaxf(1.f + sa, 1.f), 100.f);
    const float beta  = fminf(fmaxf(1.f + sb, 1.f), 100.f);
    const float am1 = alpha - 1.f, bm1 = beta - 1.f;

    // stabilizer at the beta mode (cancels in normalization; avoids underflow)
    const float den = am1 + bm1;
    float mm = (den > 0.f) ? am1 / den : 0.5f;
    mm = fminf(fmaxf(mm, 1e-6f), 1.f - 1e-6f);
    const float M2 = am1 * FAST_LOG2(mm) + bm1 * FAST_LOG2(1.f - mm);

    // ---- phase 2: quadrature, 8 lanes per row, points strided by 8 ----
    float seg[KC];
    {
        int base = 0;
#pragma unroll
        for (int i = 1; i <= KC; ++i) {
            const int n = 10 * i;
            float s = 0.f;
#pragma unroll
            for (int t = part; t < n; t += 8) {
                const float2 e = s_tab[base + t];
                s += FAST_EXP2(fmaf(am1, e.x, fmaf(bm1, e.y, -M2)));
            }
            seg[i - 1] = s;
            base += n;
        }
    }
#pragma unroll
    for (int i = 0; i < KC; ++i) {
        seg[i] += __shfl_xor(seg[i], 8, 64);
        seg[i] += __shfl_xor(seg[i], 16, 64);
        seg[i] += __shfl_xor(seg[i], 32, 64);
    }

    if (part == 0) {
        float* orow = out + (size_t)row * KC;
        const float inv_total = 1.f / seg[KC - 1];   // total = cdf_K (telescoping)
        float prev = 0.f;
        float2* o2 = reinterpret_cast<float2*>(orow);  // 40B rows are 8B-aligned
#pragma unroll
        for (int j = 0; j < KC; j += 2) {
            const float p0 = (seg[j]     - prev)   * inv_total;
            const float p1 = (seg[j + 1] - seg[j]) * inv_total;
            o2[j >> 1] = make_float2(p0, p1);
            prev = seg[j + 1];
        }
    }
}

// ---------------- Fallback: round-1 fused kernel (passed) ------------------
__global__ __launch_bounds__(256, 4) void ub_fused_kernel(
    const float* __restrict__ x, const float* __restrict__ Wa,
    const float* __restrict__ ba, const float* __restrict__ Wb,
    const float* __restrict__ bb, float* __restrict__ out,
    int B, int C, int K)
{
    __shared__ __align__(16) float s_lg[600];
    __shared__ __align__(16) float s_l1g[600];
    __shared__ __align__(16) float s_w[1024];

    const int tid = threadIdx.x;
    for (int c = tid; c < C; c += blockDim.x) {
        s_w[c]     = Wa[c];
        s_w[C + c] = Wb[c];
    }
    {
        int base = 0;
        for (int i = 1; i <= K; ++i) {
            const int n = (int)((double)NPTS_C * ((double)i / (double)K));
            const double start = EPS_C;
            const double stop  = (double)i / (double)K - EPS_C;
            const double step  = (n > 1) ? (stop - start) / (double)(n - 1) : 0.0;
            for (int j = tid; j < n; j += blockDim.x) {
                float g = (j == n - 1) ? (float)stop : (float)(start + step * (double)j);
                s_lg[base + j]  = logf(g);
                s_l1g[base + j] = log1pf(-g);
            }
            base += n;
        }
    }
    __syncthreads();

    const float ba0 = ba[0], bb0 = bb[0];
    const int wave = tid >> 6;
    const int lane = tid & 63;
    const int wavesPerBlock = blockDim.x >> 6;
    const int waveId = blockIdx.x * wavesPerBlock + wave;
    const int nWaves = gridDim.x * wavesPerBlock;

    for (int row = waveId; row < B; row += nWaves) {
        const float* xr = x + (size_t)row * C;
        float da = 0.f, db = 0.f;
        for (int c0 = 0; c0 < C; c0 += 256) {
            const float4 xv = *reinterpret_cast<const float4*>(xr + c0 + 4 * lane);
            const float4 wa = *reinterpret_cast<const float4*>(&s_w[c0 + 4 * lane]);
            const float4 wb = *reinterpret_cast<const float4*>(&s_w[C + c0 + 4 * lane]);
            da += xv.x * wa.x + xv.y * wa.y + xv.z * wa.z + xv.w * wa.w;
            db += xv.x * wb.x + xv.y * wb.y + xv.z * wb.z + xv.w * wb.w;
        }
        da = wave_reduce_sum(da) + ba0;
        db = wave_reduce_sum(db) + bb0;

        const float sa = fmaxf(da, 0.f) + log1pf(expf(-fabsf(da)));
        const float sb = fmaxf(db, 0.f) + log1pf(expf(-fabsf(db)));
        const float alpha = fminf(fmaxf(1.f + sa, 1.f), 100.f);
        const float beta  = fminf(fmaxf(1.f + sb, 1.f), 100.f);
        const float log_norm = lgammaf(alpha) + lgammaf(beta) - lgammaf(alpha + beta);
        const float am1 = alpha - 1.f, bm1 = beta - 1.f;

        float cdf_prev = 0.f, myp = 0.f;
        int base = 0;
        for (int i = 1; i <= K; ++i) {
            const int n = (int)((double)NPTS_C * ((double)i / (double)K));
            float s = 0.f;
            for (int p = lane; p < n; p += 64) {
                const float lp = fmaf(am1, s_lg[base + p],
                                 fmaf(bm1, s_l1g[base + p], -log_norm));
                s += expf(lp);
            }
            const float cdf = wave_reduce_sum(s);
            if (lane == i - 1) myp = cdf - cdf_prev;
            cdf_prev = cdf;
            base += n;
        }
        if (lane < K)
            out[(size_t)row * K + lane] = myp / cdf_prev;
    }
}

extern "C" void kernel_launch(void* const* d_in, const int* in_sizes, int n_in,
                              void* d_out, int out_size, void* d_ws, size_t ws_size,
                              hipStream_t stream) {
    const float* x  = (const float*)d_in[0];
    const float* Wa = (const float*)d_in[1];
    const float* ba = (const float*)d_in[2];
    const float* Wb = (const float*)d_in[3];
    const float* bb = (const float*)d_in[4];
    float* out = (float*)d_out;

    const int C = in_sizes[1];           // 512
    const int B = in_sizes[0] / C;       // 65536
    const int K = out_size / B;          // 10

    const bool fast_ok = (C == 512) && (K == 10) && (B % 32 == 0);

    if (fast_ok) {
        fused512_kernel<<<B / 32, 256, 0, stream>>>(x, Wa, ba, Wb, bb, out);
    } else {
        int nblocks = (B + 3) / 4;
        if (nblocks > 2048) nblocks = 2048;
        ub_fused_kernel<<<nblocks, 256, 0, stream>>>(x, Wa, ba, Wb, bb, out, B, C, K);
    }
}

// Round 10
// 29.963 us; speedup vs baseline: 1.2306x; 1.1317x over previous
//
#include <hip/hip_runtime.h>
#include <math.h>

#define NPTS_C 100
#define EPS_C 1e-8

#if defined(__has_builtin)
# if __has_builtin(__builtin_amdgcn_exp2f)
#  define FAST_EXP2(x) __builtin_amdgcn_exp2f(x)
#  define FAST_LOG2(x) __builtin_amdgcn_logf(x)
# else
#  define FAST_EXP2(x) exp2f(x)
#  define FAST_LOG2(x) log2f(x)
# endif
#else
# define FAST_EXP2(x) exp2f(x)
# define FAST_LOG2(x) log2f(x)
#endif

#define LOG2E_F 1.44269504088896340736f
#define LN2_F   0.69314718055994530942f

__device__ __forceinline__ float dot4(float4 a, float4 b) {
    return a.x * b.x + a.y * b.y + a.z * b.z + a.w * b.w;
}

__device__ __forceinline__ float wave_reduce_sum(float v) {
#pragma unroll
    for (int m = 1; m < 64; m <<= 1)
        v += __shfl_xor(v, m, 64);
    return v;
}

// ---------------- fast path constants (C=512, K=10, NPTS=100) --------------
constexpr int KC   = 10;
constexpr int NTAB = 550;   // sum_{i=1..10} 10*i

// Block = 256 threads = 4 waves; each wave owns 8 consecutive rows.
// CONTIGUOUS-LOAD layout: load instr j reads float4 index row0*128 + j*64 + l
// -> 64 consecutive float4 = 1KB contiguous per instruction (streaming
// pattern, like the 7 TB/s fills). Weights live in 4 per-lane registers
// (col4 = l and 64+l); no LDS in the dot loop.
// Reduction: xor1/2/4 on the 8 per-row partials (group sums), 8-way select
// by r8, xor8/16/32 -> row r's (da,db) lands in lanes r8==r, exactly what
// the quad phase consumes. Quad phase unchanged from R7/R9 (proven).
__global__ __launch_bounds__(256, 4) void fused512_kernel(
    const float* __restrict__ x, const float* __restrict__ Wa,
    const float* __restrict__ ba, const float* __restrict__ Wb,
    const float* __restrict__ bb, float* __restrict__ out)
{
    __shared__ __align__(16) float2 s_tab[NTAB];   // (log2 g, log2(1-g)), fp32 grid

    const int tid = threadIdx.x;

    // row-invariant log2 tables (fp32 grid, matches ref; last point of last
    // segment rounds to 1.0f -> log2f(0) = -inf -> exp2 -> 0)
    {
        int base = 0;
#pragma unroll
        for (int i = 1; i <= KC; ++i) {
            const int n = 10 * i;
            const double start = EPS_C;
            const double stop  = (double)i / (double)KC - EPS_C;
            const double step  = (stop - start) / (double)(n - 1);
            for (int j = tid; j < n; j += 256) {
                const double g = (j == n - 1) ? stop : start + step * (double)j;
                const float g32 = (float)g;
                s_tab[base + j] = make_float2(log2f(g32), log2f(1.0f - g32));
            }
            base += n;
        }
    }
    __syncthreads();

    const int lane = tid & 63;
    const int wv   = tid >> 6;
    const int r8   = lane & 7;    // quad phase: which of the wave's 8 rows
    const int part = lane >> 3;   // quad phase: slice of the row's points
    const float ba0 = ba[0], bb0 = bb[0];

    // per-lane weight registers: lane l covers col4 indices l and 64+l
    const float4* Wa4 = reinterpret_cast<const float4*>(Wa);
    const float4* Wb4 = reinterpret_cast<const float4*>(Wb);
    const float4 wa_lo = Wa4[lane], wa_hi = Wa4[64 + lane];
    const float4 wb_lo = Wb4[lane], wb_hi = Wb4[64 + lane];

    const int row0 = blockIdx.x * 32 + wv * 8;
    const float4* px = reinterpret_cast<const float4*>(x) + (size_t)row0 * 128 + lane;

    // ---- phase 1: 16 contiguous 1KB loads, burst-issued ----
    float4 xv[16];
#pragma unroll
    for (int j = 0; j < 16; ++j)
        xv[j] = px[j * 64];

    float acca[8], accb[8];
#pragma unroll
    for (int r = 0; r < 8; ++r) {
        acca[r] = dot4(xv[2 * r], wa_lo) + dot4(xv[2 * r + 1], wa_hi);
        accb[r] = dot4(xv[2 * r], wb_lo) + dot4(xv[2 * r + 1], wb_hi);
    }

    // ---- reduction: group sums (xor 1/2/4), select by r8, cross-group ----
#pragma unroll
    for (int r = 0; r < 8; ++r) {
        acca[r] += __shfl_xor(acca[r], 1, 64);
        accb[r] += __shfl_xor(accb[r], 1, 64);
        acca[r] += __shfl_xor(acca[r], 2, 64);
        accb[r] += __shfl_xor(accb[r], 2, 64);
        acca[r] += __shfl_xor(acca[r], 4, 64);
        accb[r] += __shfl_xor(accb[r], 4, 64);
    }
    float da = acca[0], db = accb[0];
#pragma unroll
    for (int r = 1; r < 8; ++r) {
        const bool sel = (r8 == r);
        da = sel ? acca[r] : da;
        db = sel ? accb[r] : db;
    }
    da += __shfl_xor(da, 8, 64);  db += __shfl_xor(db, 8, 64);
    da += __shfl_xor(da, 16, 64); db += __shfl_xor(db, 16, 64);
    da += __shfl_xor(da, 32, 64); db += __shfl_xor(db, 32, 64);
    da += ba0; db += bb0;

    // ---- per-row scalars (8-way redundant; hw exp2/log2 forms) ----
    const float ua = FAST_EXP2(-fabsf(da) * LOG2E_F);
    const float ub = FAST_EXP2(-fabsf(db) * LOG2E_F);
    const float sa = fmaxf(da, 0.f) + FAST_LOG2(1.f + ua) * LN2_F;
    const float sb = fmaxf(db, 0.f) + FAST_LOG2(1.f + ub) * LN2_F;
    const float alpha = fminf(fmaxf(1.f + sa, 1.f), 100.f);
    const float beta  = fminf(fmaxf(1.f + sb, 1.f), 100.f);
    const float am1 = alpha - 1.f, bm1 = beta - 1.f;

    // stabilizer at the beta mode (cancels in normalization; avoids underflow)
    const float den = am1 + bm1;
    float mm = (den > 0.f) ? am1 / den : 0.5f;
    mm = fminf(fmaxf(mm, 1e-6f), 1.f - 1e-6f);
    const float M2 = am1 * FAST_LOG2(mm) + bm1 * FAST_LOG2(1.f - mm);

    // ---- phase 2: quadrature, 8 lanes per row, points strided by 8 ----
    float seg[KC];
    {
        int base = 0;
#pragma unroll
        for (int i = 1; i <= KC; ++i) {
            const int n = 10 * i;
            float s = 0.f;
#pragma unroll
            for (int t = part; t < n; t += 8) {
                const float2 e = s_tab[base + t];
                s += FAST_EXP2(fmaf(am1, e.x, fmaf(bm1, e.y, -M2)));
            }
            seg[i - 1] = s;
            base += n;
        }
    }
#pragma unroll
    for (int i = 0; i < KC; ++i) {
        seg[i] += __shfl_xor(seg[i], 8, 64);
        seg[i] += __shfl_xor(seg[i], 16, 64);
        seg[i] += __shfl_xor(seg[i], 32, 64);
    }

    if (part == 0) {
        float* orow = out + (size_t)(row0 + r8) * KC;
        const float inv_total = 1.f / seg[KC - 1];   // total = cdf_K (telescoping)
        float prev = 0.f;
        float2* o2 = reinterpret_cast<float2*>(orow);  // 40B rows are 8B-aligned
#pragma unroll
        for (int j = 0; j < KC; j += 2) {
            const float p0 = (seg[j]     - prev)   * inv_total;
            const float p1 = (seg[j + 1] - seg[j]) * inv_total;
            o2[j >> 1] = make_float2(p0, p1);
            prev = seg[j + 1];
        }
    }
}

// ---------------- Fallback: round-1 fused kernel (passed) ------------------
__global__ __launch_bounds__(256, 4) void ub_fused_kernel(
    const float* __restrict__ x, const float* __restrict__ Wa,
    const float* __restrict__ ba, const float* __restrict__ Wb,
    const float* __restrict__ bb, float* __restrict__ out,
    int B, int C, int K)
{
    __shared__ __align__(16) float s_lg[600];
    __shared__ __align__(16) float s_l1g[600];
    __shared__ __align__(16) float s_w[1024];

    const int tid = threadIdx.x;
    for (int c = tid; c < C; c += blockDim.x) {
        s_w[c]     = Wa[c];
        s_w[C + c] = Wb[c];
    }
    {
        int base = 0;
        for (int i = 1; i <= K; ++i) {
            const int n = (int)((double)NPTS_C * ((double)i / (double)K));
            const double start = EPS_C;
            const double stop  = (double)i / (double)K - EPS_C;
            const double step  = (n > 1) ? (stop - start) / (double)(n - 1) : 0.0;
            for (int j = tid; j < n; j += blockDim.x) {
                float g = (j == n - 1) ? (float)stop : (float)(start + step * (double)j);
                s_lg[base + j]  = logf(g);
                s_l1g[base + j] = log1pf(-g);
            }
            base += n;
        }
    }
    __syncthreads();

    const float ba0 = ba[0], bb0 = bb[0];
    const int wave = tid >> 6;
    const int lane = tid & 63;
    const int wavesPerBlock = blockDim.x >> 6;
    const int waveId = blockIdx.x * wavesPerBlock + wave;
    const int nWaves = gridDim.x * wavesPerBlock;

    for (int row = waveId; row < B; row += nWaves) {
        const float* xr = x + (size_t)row * C;
        float da = 0.f, db = 0.f;
        for (int c0 = 0; c0 < C; c0 += 256) {
            const float4 xv = *reinterpret_cast<const float4*>(xr + c0 + 4 * lane);
            const float4 wa = *reinterpret_cast<const float4*>(&s_w[c0 + 4 * lane]);
            const float4 wb = *reinterpret_cast<const float4*>(&s_w[C + c0 + 4 * lane]);
            da += xv.x * wa.x + xv.y * wa.y + xv.z * wa.z + xv.w * wa.w;
            db += xv.x * wb.x + xv.y * wb.y + xv.z * wb.z + xv.w * wb.w;
        }
        da = wave_reduce_sum(da) + ba0;
        db = wave_reduce_sum(db) + bb0;

        const float sa = fmaxf(da, 0.f) + log1pf(expf(-fabsf(da)));
        const float sb = fmaxf(db, 0.f) + log1pf(expf(-fabsf(db)));
        const float alpha = fminf(fmaxf(1.f + sa, 1.f), 100.f);
        const float beta  = fminf(fmaxf(1.f + sb, 1.f), 100.f);
        const float log_norm = lgammaf(alpha) + lgammaf(beta) - lgammaf(alpha + beta);
        const float am1 = alpha - 1.f, bm1 = beta - 1.f;

        float cdf_prev = 0.f, myp = 0.f;
        int base = 0;
        for (int i = 1; i <= K; ++i) {
            const int n = (int)((double)NPTS_C * ((double)i / (double)K));
            float s = 0.f;
            for (int p = lane; p < n; p += 64) {
                const float lp = fmaf(am1, s_lg[base + p],
                                 fmaf(bm1, s_l1g[base + p], -log_norm));
                s += expf(lp);
            }
            const float cdf = wave_reduce_sum(s);
            if (lane == i - 1) myp = cdf - cdf_prev;
            cdf_prev = cdf;
            base += n;
        }
        if (lane < K)
            out[(size_t)row * K + lane] = myp / cdf_prev;
    }
}

extern "C" void kernel_launch(void* const* d_in, const int* in_sizes, int n_in,
                              void* d_out, int out_size, void* d_ws, size_t ws_size,
                              hipStream_t stream) {
    const float* x  = (const float*)d_in[0];
    const float* Wa = (const float*)d_in[1];
    const float* ba = (const float*)d_in[2];
    const float* Wb = (const float*)d_in[3];
    const float* bb = (const float*)d_in[4];
    float* out = (float*)d_out;

    const int C = in_sizes[1];           // 512
    const int B = in_sizes[0] / C;       // 65536
    const int K = out_size / B;          // 10

    const bool fast_ok = (C == 512) && (K == 10) && (B % 32 == 0);

    if (fast_ok) {
        fused512_kernel<<<B / 32, 256, 0, stream>>>(x, Wa, ba, Wb, bb, out);
    } else {
        int nblocks = (B + 3) / 4;
        if (nblocks > 2048) nblocks = 2048;
        ub_fused_kernel<<<nblocks, 256, 0, stream>>>(x, Wa, ba, Wb, bb, out, B, C, K);
    }
}